// Round 3
// baseline (529.080 us; speedup 1.0000x reference)
//
#include <hip/hip_runtime.h>

#define NT   49      // tokens per window
#define HD   32      // head dim
#define NH   4
#define DIM  128
#define SCALEQ 0.17677669529663687f  // 32^-0.5

typedef __attribute__((ext_vector_type(8))) short short8;
typedef __attribute__((ext_vector_type(4))) short short4v;
typedef __attribute__((ext_vector_type(4))) float floatx4;
// may_alias versions: all LDS/global type-punned accesses go through these so
// TBAA cannot reorder stores/loads across the barrier-free phase chain.
typedef short8 short8a __attribute__((may_alias));
typedef short4v short4a __attribute__((may_alias));
typedef unsigned long long ulla __attribute__((may_alias));
typedef unsigned long long ull;

__device__ __forceinline__ short f2b(float f) {
    union { float f; unsigned u; } v; v.f = f;
    return (short)((v.u + 0x7fffu + ((v.u >> 16) & 1u)) >> 16);  // RNE fp32->bf16
}
__device__ __forceinline__ float b2f(short s) {
    union { unsigned u; float f; } v; v.u = ((unsigned)(unsigned short)s) << 16;
    return v.f;
}

// K=16 MFMA for the PV step: B-frag wants 4 consecutive k per lane, which is
// exactly the C-layout phase 1 produces for V -> V never touches LDS.
// Fallback (if the _1k builtin is absent): zero-padded K=32. Placing the 4
// valid elements at e=0..3 of each lane maps them to k32=qq*8+e identically
// for A and B, so the contraction equals the K=16 product exactly.
#if __has_builtin(__builtin_amdgcn_mfma_f32_16x16x16bf16_1k)
__device__ __forceinline__ floatx4 MFMA16(short4v a, short4v b, floatx4 c) {
    return __builtin_amdgcn_mfma_f32_16x16x16bf16_1k(a, b, c, 0, 0, 0);
}
#else
__device__ __forceinline__ floatx4 MFMA16(short4v a, short4v b, floatx4 c) {
    short8 a8 = {a[0], a[1], a[2], a[3], 0, 0, 0, 0};
    short8 b8 = {b[0], b[1], b[2], b[3], 0, 0, 0, 0};
    return __builtin_amdgcn_mfma_f32_16x16x32_bf16(a8, b8, c, 0, 0, 0);
}
#endif

// ---------- prologue ----------
// 64 blocks (one per window). Stage ridx/btab/mask in LDS, emit the combined
// bias+mask table (cmb) in MFMA frag layout + convert weights to bf16.
// cmb[wdw][h][(it*4+jt)*256 + qq*64 + cc*4 + r] bf16 = bias[h] + mask[wdw];
// col>=49 -> -1e30 (masks key pads via C-init), row>=49 -> 0. wqkv Q-section
// pre-scaled by hd^-0.5.
__global__ __launch_bounds__(256) void wmsa_prep(
        const float* __restrict__ qkvw, const float* __restrict__ projw,
        const float* __restrict__ btab, const int* __restrict__ ridx,
        const float* __restrict__ mask,
        short* __restrict__ wqkv, short* __restrict__ wproj,
        short* __restrict__ cmb) {
    __shared__ __align__(16) int   s_ridx[NT * NT];        // 9604 B
    __shared__ __align__(16) float s_btab[169 * 4];        // 2704 B (float4 rows)
    __shared__ __align__(16) float s_mask[NT * NT];        // 9604 B

    const int wdw = blockIdx.x;
    const int tid = threadIdx.x;

    // ---- weight conversion: one float4 group per thread (grid covers all) ----
    {
        int g = wdw * 256 + tid;          // 0..16383; 3*128*128/4 = 12288 qkv groups
        const float* src = (g < 12288) ? (qkvw + g * 4) : (projw + (g - 12288) * 4);
        float4 v = *(const float4*)src;
        float s = (g < 4096) ? SCALEQ : 1.0f;   // first DIM*DIM elements = Q rows
        ull pk =  (ull)(unsigned short)f2b(v.x * s)
                | ((ull)(unsigned short)f2b(v.y * s) << 16)
                | ((ull)(unsigned short)f2b(v.z * s) << 32)
                | ((ull)(unsigned short)f2b(v.w * s) << 48);
        if (g < 12288) *(ulla*)(wqkv + g * 4) = pk;
        else           *(ulla*)(wproj + (g - 12288) * 4) = pk;
    }

    // ---- stage gather tables (coalesced) ----
    for (int i = tid; i < NT * NT; i += 256) s_ridx[i] = ridx[i];
    for (int i = tid; i < 169 * 4; i += 256) s_btab[i] = btab[i];
    {
        const float* mw = mask + (size_t)wdw * NT * NT;
        for (int i = tid; i < NT * NT; i += 256) s_mask[i] = mw[i];
    }
    __syncthreads();

    // ---- emit combined table for this window: 4 heads x 4096 bf16 ----
    // group g encodes (it,jt,qq,cc); the 4 consecutive shorts are r=0..3.
    #pragma unroll
    for (int gi = 0; gi < 4; ++gi) {
        int g = gi * 256 + tid;                       // 0..1023
        int cc = g & 15, qq = (g >> 4) & 3, tile = g >> 6;
        int it = tile >> 2, jt = tile & 3;
        int col = jt * 16 + cc;
        int rowb = it * 16 + qq * 4;
        if (col >= NT) {
            ull m16 = (unsigned short)f2b(-1e30f);
            ull pk = m16 | (m16 << 16) | (m16 << 32) | (m16 << 48);
            #pragma unroll
            for (int h = 0; h < NH; ++h)
                *(ulla*)(cmb + (((size_t)wdw * NH + h) << 12) + g * 4) = pk;
        } else {
            float bt[4][4], mv[4];
            #pragma unroll
            for (int r = 0; r < 4; ++r) {
                int row = rowb + r;
                if (row >= NT) {
                    bt[r][0] = bt[r][1] = bt[r][2] = bt[r][3] = 0.f;
                    mv[r] = 0.f;
                } else {
                    int ri = s_ridx[row * NT + col];
                    float4 b4 = *(const float4*)(s_btab + ri * 4);  // all 4 heads
                    bt[r][0] = b4.x; bt[r][1] = b4.y; bt[r][2] = b4.z; bt[r][3] = b4.w;
                    mv[r] = s_mask[row * NT + col];
                }
            }
            #pragma unroll
            for (int h = 0; h < NH; ++h) {
                ull pk =  (ull)(unsigned short)f2b(bt[0][h] + mv[0])
                        | ((ull)(unsigned short)f2b(bt[1][h] + mv[1]) << 16)
                        | ((ull)(unsigned short)f2b(bt[2][h] + mv[2]) << 32)
                        | ((ull)(unsigned short)f2b(bt[3][h] + mv[3]) << 48);
                *(ulla*)(cmb + (((size_t)wdw * NH + h) << 12) + g * 4) = pk;
            }
        }
    }
}

// LDS pool (32768 B -> 5 blocks/CU, was 51200/3). Per-wave region R=8192 B:
//   Q @+0    [64 rows][32] bf16, XOR-swizzled 8-short groups   = 4096
//   K @+4096 same                                              = 4096
//   P @+0    [64 rows][64] bf16 3-bit-swizzled (overlays Q+K)  = 8192
//   V lives in REGISTERS (16 VGPR) and feeds K=16 PV MFMAs directly.
// Block-shared, phase-disjoint overlays:
//   X @0 [64][136] bf16 = 17408 (dead after barrier 2)
//   O @0 [64][136] bf16 = 17408 (after barrier 3)
#define RWAVE 8192
#define OSTR  136
#define LDSB  32768

__global__ __launch_bounds__(256, 5) void wmsa_main(
    const float* __restrict__ x,
    const float* __restrict__ qkvb, const float* __restrict__ projb,
    const short* __restrict__ wqkv, const short* __restrict__ wproj,
    const short* __restrict__ cmb, float* __restrict__ out)
{
    __shared__ __align__(16) char pool[LDSB];
    short* lds = (short*)pool;

    const int b    = blockIdx.x;
    const int wdw  = b & 63;
    const int tid  = threadIdx.x;
    const int wave = tid >> 6;
    const int lane = tid & 63;
    const int qq   = lane >> 4;        // quad 0..3
    const int cc   = lane & 15;
    const int ccl  = cc & 7, cch = cc >> 3, cm3 = cc & 3;

    // ---- prefetch: jt6=0 B-frags + all 6 qkv biases (complete during staging) ----
    const int colbase = wave * 32 + cc;
    short8 bfc[4], bfn[4];
    #pragma unroll
    for (int ks = 0; ks < 4; ++ks)
        bfc[ks] = *(const short8a*)(wqkv + colbase * DIM + ks * 32 + qq * 8);
    float biasv[6];
    #pragma unroll
    for (int j = 0; j < 6; ++j)
        biasv[j] = qkvb[(j >> 1) * DIM + colbase + (j & 1) * 16];

    // ---------------- Phase 0: stage x -> bf16 LDS (stride 136), zero pad rows ----------------
    {
        const float* xb = x + (size_t)b * NT * DIM;
        for (int i = tid; i < NT * 32; i += 256) {
            int t = i >> 5, c4 = (i & 31) << 2;
            float4 v = *(const float4*)(xb + t * DIM + c4);
            ull pk =  (ull)(unsigned short)f2b(v.x)
                    | ((ull)(unsigned short)f2b(v.y) << 16)
                    | ((ull)(unsigned short)f2b(v.z) << 32)
                    | ((ull)(unsigned short)f2b(v.w) << 48);
            *(ulla*)(lds + t * 136 + c4) = pk;
        }
        for (int i = tid; i < (64 - NT) * 32; i += 256) {   // zero rows 49..63
            int t = NT + (i >> 5), c4 = (i & 31) << 2;
            *(ulla*)(lds + t * 136 + c4) = 0ull;
        }
    }
    __syncthreads();   // B1: X staged

    // A-frags of X for all 4 row tiles (held in regs through phase 1)
    short8 af[4][4];
    #pragma unroll
    for (int it = 0; it < 4; ++it)
        #pragma unroll
        for (int ks = 0; ks < 4; ++ks)
            af[it][ks] = *(const short8a*)(lds + (it * 16 + cc) * 136 + ks * 32 + qq * 8);
    __syncthreads();   // B2: X reads done; per-wave regions may be written

    short* qw = (short*)(pool + wave * RWAVE);
    short* kw = qw + 2048;     // +4096 B
    short* pw = qw;            // P overlays Q+K after S

    // V in registers: vq[hlf][it] = 4 consecutive tokens (t0..t0+3, bf16) for
    // dim hlf*16+cc — exactly the 16x16x16 B-frag layout. Static indices only.
    short4v vq[2][4];

    // ---------------- Phase 1: wave h computes Q/K/V of head h (pipelined B-frags) ----------------
    #pragma unroll
    for (int jt6 = 0; jt6 < 6; ++jt6) {
        const int sec = jt6 >> 1, hlf = jt6 & 1;             // compile-time
        if (jt6 < 5) {                                        // prefetch next iteration's frags
            const int cn = ((jt6 + 1) >> 1) * DIM + colbase + ((jt6 + 1) & 1) * 16;
            #pragma unroll
            for (int ks = 0; ks < 4; ++ks)
                bfn[ks] = *(const short8a*)(wqkv + cn * DIM + ks * 32 + qq * 8);
        }
        float bias = biasv[jt6];
        if (sec == 0) bias *= SCALEQ;
        const floatx4 cinit = {bias, bias, bias, bias};
        #pragma unroll
        for (int it = 0; it < 4; ++it) {
            floatx4 acc = cinit;
            #pragma unroll
            for (int ks = 0; ks < 4; ++ks)
                acc = __builtin_amdgcn_mfma_f32_16x16x32_bf16(af[it][ks], bfc[ks], acc, 0, 0, 0);
            if (sec == 2) {                                   // V: stays in registers
                short4v pv;
                pv[0] = f2b(acc[0]); pv[1] = f2b(acc[1]);
                pv[2] = f2b(acc[2]); pv[3] = f2b(acc[3]);
                vq[hlf][it] = pv;
            } else {                                          // Q/K: [t][d] swizzled
                short* dst = (sec == 0) ? qw : kw;
                int gb = hlf * 2 + cch;                       // d>>3
                #pragma unroll
                for (int r = 0; r < 4; ++r) {                 // t&3 == r
                    int t = it * 16 + qq * 4 + r;
                    dst[t * 32 + ((gb ^ r) << 3) + ccl] = f2b(acc[r]);
                }
            }
        }
        #pragma unroll
        for (int ks = 0; ks < 4; ++ks) bfc[ks] = bfn[ks];
    }

    // prefetch all 16 S-tile C-inits (bias+mask combined, bf16 frag layout);
    // placed after phase 1 (not hoisted) to keep VGPR pressure under the
    // 5-waves/EU budget.
    short4v cm[16];
    {
        const short* cw = cmb + (((size_t)wdw * NH + wave) << 12);
        #pragma unroll
        for (int t16 = 0; t16 < 16; ++t16)
            cm[t16] = *(const short4a*)(cw + t16 * 256 + qq * 64 + cc * 4);
    }
    __asm__ volatile("" ::: "memory");   // intra-wave phase fence: QKV stores -> S loads

    // ---------------- Phase 2: S = Q K^T (+combined C-init), exp, store RAW P ----------------
    // P stored UNNORMALIZED; denominators come from rowsum = P@1 MFMAs in
    // phase 3; O scaled by 1/rowsum after PV. P swizzle is 3-bit:
    // g = (col>>3) ^ (t&3) ^ (((t>>2)&1)<<2) — third bit makes the phase-3
    // b64 reads 2-way banked (free) instead of 4-way.
    {
        short8 qf[4], kf[4];
        #pragma unroll
        for (int t = 0; t < 4; ++t) {
            qf[t] = *(const short8a*)(qw + (t * 16 + cc) * 32 + ((qq ^ cm3) << 3));
            kf[t] = *(const short8a*)(kw + (t * 16 + cc) * 32 + ((qq ^ cm3) << 3));
        }
        #pragma unroll
        for (int it = 0; it < 4; ++it) {
            floatx4 s[4];
            #pragma unroll
            for (int jt = 0; jt < 4; ++jt) {
                short4v cb = cm[it * 4 + jt];
                floatx4 ci = {b2f(cb.x), b2f(cb.y), b2f(cb.z), b2f(cb.w)};
                s[jt] = __builtin_amdgcn_mfma_f32_16x16x32_bf16(qf[it], kf[jt], ci, 0, 0, 0);
            }
            #pragma unroll
            for (int r = 0; r < 4; ++r) {
                int t = it * 16 + qq * 4 + r;
                #pragma unroll
                for (int jt = 0; jt < 4; ++jt) {
                    float ee = __expf(s[jt][r]);   // pads -> exp(-1e30)=0
                    int g = (jt * 2 + cch) ^ r ^ ((qq & 1) << 2);
                    pw[t * 64 + (g << 3) + ccl] = f2b(ee);
                }
            }
        }
    }
    __asm__ volatile("" ::: "memory");   // intra-wave phase fence: P stores -> PV loads

    // ---------------- Phase 3: O = P @ V and rowsum = P @ 1 (K=16 MFMAs, V in regs) ----------------
    floatx4 o[4][2], ssum[4];
    #pragma unroll
    for (int it = 0; it < 4; ++it) {
        o[it][0] = (floatx4){0.f, 0.f, 0.f, 0.f};
        o[it][1] = (floatx4){0.f, 0.f, 0.f, 0.f};
        ssum[it] = (floatx4){0.f, 0.f, 0.f, 0.f};
    }
    const short BONE = (short)0x3F80;    // bf16 1.0
    const short4v ones4 = {BONE, BONE, BONE, BONE};
    #pragma unroll
    for (int rt = 0; rt < 4; ++rt) {
        #pragma unroll
        for (int kt = 0; kt < 4; ++kt) {
            // A-frag: P[row=rt*16+cc][k=kt*16+qq*4..+3], 3-bit swizzle
            int g = (kt * 2 + (qq >> 1)) ^ cm3 ^ (((cc >> 2) & 1) << 2);
            short4v pf = *(const short4a*)(pw + (rt * 16 + cc) * 64 + (g << 3) + (qq & 1) * 4);
            o[rt][0] = MFMA16(pf, vq[0][kt], o[rt][0]);
            o[rt][1] = MFMA16(pf, vq[1][kt], o[rt][1]);
            ssum[rt] = MFMA16(pf, ones4, ssum[rt]);
        }
    }
    // normalize O rows by 1/rowsum (rowsum lands in the same C-layout rows as o)
    #pragma unroll
    for (int it = 0; it < 4; ++it)
        #pragma unroll
        for (int r = 0; r < 4; ++r) {
            float inv = 1.0f / ssum[it][r];
            o[it][0][r] *= inv;
            o[it][1][r] *= inv;
        }

    // prefetch proj B-frags jt=0,1 + all 8 proj biases (issued before the barriers,
    // cannot be sunk past them -> latency overlaps O round-trip)
    short8 pcur[4], pnxt[4];
    float pbv[8];
    #pragma unroll
    for (int ks = 0; ks < 4; ++ks) {
        pcur[ks] = *(const short8a*)(wproj + cc * DIM + ks * 32 + qq * 8);
        pnxt[ks] = *(const short8a*)(wproj + (16 + cc) * DIM + ks * 32 + qq * 8);
    }
    #pragma unroll
    for (int j = 0; j < 8; ++j) pbv[j] = projb[j * 16 + cc];

    __syncthreads();   // B3: all P reads done -> O may overlay per-wave regions

    short* ow = (short*)pool;   // O [64 tokens][OSTR=136], features 0..127
    #pragma unroll
    for (int it = 0; it < 4; ++it)
        #pragma unroll
        for (int jv = 0; jv < 2; ++jv)
            #pragma unroll
            for (int r = 0; r < 4; ++r) {
                int t = it * 16 + qq * 4 + r;
                ow[t * OSTR + wave * 32 + jv * 16 + cc] = f2b(o[it][jv][r]);
            }
    __syncthreads();   // B4: O visible

    // ---------------- Phase 4: proj GEMM (depth-2 pipelined B-frags) ----------------
    {
        short8 a2[4];
        #pragma unroll
        for (int ks = 0; ks < 4; ++ks)
            a2[ks] = *(const short8a*)(ow + (wave * 16 + cc) * OSTR + ks * 32 + qq * 8);
        float* outb = out + (size_t)b * NT * DIM;
        #pragma unroll
        for (int jt = 0; jt < 8; ++jt) {
            short8 pfut[4];
            if (jt < 6) {
                int cn = (jt + 2) * 16 + cc;
                #pragma unroll
                for (int ks = 0; ks < 4; ++ks)
                    pfut[ks] = *(const short8a*)(wproj + cn * DIM + ks * 32 + qq * 8);
            }
            float pb = pbv[jt];
            floatx4 acc = {pb, pb, pb, pb};
            #pragma unroll
            for (int ks = 0; ks < 4; ++ks)
                acc = __builtin_amdgcn_mfma_f32_16x16x32_bf16(a2[ks], pcur[ks], acc, 0, 0, 0);
            int col = jt * 16 + cc;
            #pragma unroll
            for (int r = 0; r < 4; ++r) {
                int row = wave * 16 + qq * 4 + r;
                if (row < NT) outb[row * DIM + col] = acc[r];
            }
            #pragma unroll
            for (int ks = 0; ks < 4; ++ks) { pcur[ks] = pnxt[ks]; pnxt[ks] = pfut[ks]; }
        }
    }
}

extern "C" void kernel_launch(void* const* d_in, const int* in_sizes, int n_in,
                              void* d_out, int out_size, void* d_ws, size_t ws_size,
                              hipStream_t stream) {
    const float* x     = (const float*)d_in[0];   // (4096,49,128)
    const float* mask  = (const float*)d_in[1];   // (64,49,49)
    const float* qkvw  = (const float*)d_in[2];   // (384,128)
    const float* qkvb  = (const float*)d_in[3];   // (384)
    const float* projw = (const float*)d_in[4];   // (128,128)
    const float* projb = (const float*)d_in[5];   // (128)
    const float* btab  = (const float*)d_in[6];   // (169,4)
    const int*   ridx  = (const int*)d_in[7];     // (49,49)
    float* outp = (float*)d_out;

    short* wqkv  = (short*)d_ws;                      //   98304 B
    short* wproj = (short*)((char*)d_ws + 98304);     //   32768 B
    short* cmb   = (short*)((char*)d_ws + 131072);    // 2097152 B (total 2.23 MB)

    wmsa_prep<<<64, 256, 0, stream>>>(qkvw, projw, btab, ridx, mask, wqkv, wproj, cmb);
    wmsa_main<<<4096, 256, 0, stream>>>(x, qkvb, projb, wqkv, wproj, cmb, outp);
}

// Round 4
// 295.710 us; speedup vs baseline: 1.7892x; 1.7892x over previous
//
#include <hip/hip_runtime.h>

#define NT   49      // tokens per window
#define HD   32      // head dim
#define NH   4
#define DIM  128
#define SCALEQ 0.17677669529663687f  // 32^-0.5

typedef __attribute__((ext_vector_type(8))) short short8;
typedef __attribute__((ext_vector_type(4))) short short4v;
typedef __attribute__((ext_vector_type(4))) float floatx4;
// may_alias versions: all LDS/global type-punned accesses go through these so
// TBAA cannot reorder stores/loads across the barrier-free phase chain.
typedef short8 short8a __attribute__((may_alias));
typedef short4v short4a __attribute__((may_alias));
typedef unsigned long long ulla __attribute__((may_alias));
typedef unsigned long long ull;

__device__ __forceinline__ short f2b(float f) {
    union { float f; unsigned u; } v; v.f = f;
    return (short)((v.u + 0x7fffu + ((v.u >> 16) & 1u)) >> 16);  // RNE fp32->bf16
}
__device__ __forceinline__ float b2f(short s) {
    union { unsigned u; float f; } v; v.u = ((unsigned)(unsigned short)s) << 16;
    return v.f;
}

// K=16 MFMA for the PV step: B-frag wants 4 consecutive k per lane, which is
// exactly the C-layout phase 1 produces for V -> V never touches LDS.
// Fallback (if the _1k builtin is absent): zero-padded K=32. Placing the 4
// valid elements at e=0..3 of each lane maps them to k32=qq*8+e identically
// for A and B, so the contraction equals the K=16 product exactly.
#if __has_builtin(__builtin_amdgcn_mfma_f32_16x16x16bf16_1k)
__device__ __forceinline__ floatx4 MFMA16(short4v a, short4v b, floatx4 c) {
    return __builtin_amdgcn_mfma_f32_16x16x16bf16_1k(a, b, c, 0, 0, 0);
}
#else
__device__ __forceinline__ floatx4 MFMA16(short4v a, short4v b, floatx4 c) {
    short8 a8 = {a[0], a[1], a[2], a[3], 0, 0, 0, 0};
    short8 b8 = {b[0], b[1], b[2], b[3], 0, 0, 0, 0};
    return __builtin_amdgcn_mfma_f32_16x16x32_bf16(a8, b8, c, 0, 0, 0);
}
#endif

// ---------- prologue ----------
// 64 blocks (one per window). Stage ridx/btab/mask in LDS, emit the combined
// bias+mask table (cmb) in MFMA frag layout + convert weights to bf16.
// cmb[wdw][h][(it*4+jt)*256 + qq*64 + cc*4 + r] bf16 = bias[h] + mask[wdw];
// col>=49 -> -1e30 (masks key pads via C-init), row>=49 -> 0. wqkv Q-section
// pre-scaled by hd^-0.5.
__global__ __launch_bounds__(256) void wmsa_prep(
        const float* __restrict__ qkvw, const float* __restrict__ projw,
        const float* __restrict__ btab, const int* __restrict__ ridx,
        const float* __restrict__ mask,
        short* __restrict__ wqkv, short* __restrict__ wproj,
        short* __restrict__ cmb) {
    __shared__ __align__(16) int   s_ridx[NT * NT];        // 9604 B
    __shared__ __align__(16) float s_btab[169 * 4];        // 2704 B (float4 rows)
    __shared__ __align__(16) float s_mask[NT * NT];        // 9604 B

    const int wdw = blockIdx.x;
    const int tid = threadIdx.x;

    // ---- weight conversion: one float4 group per thread (grid covers all) ----
    {
        int g = wdw * 256 + tid;          // 0..16383; 3*128*128/4 = 12288 qkv groups
        const float* src = (g < 12288) ? (qkvw + g * 4) : (projw + (g - 12288) * 4);
        float4 v = *(const float4*)src;
        float s = (g < 4096) ? SCALEQ : 1.0f;   // first DIM*DIM elements = Q rows
        ull pk =  (ull)(unsigned short)f2b(v.x * s)
                | ((ull)(unsigned short)f2b(v.y * s) << 16)
                | ((ull)(unsigned short)f2b(v.z * s) << 32)
                | ((ull)(unsigned short)f2b(v.w * s) << 48);
        if (g < 12288) *(ulla*)(wqkv + g * 4) = pk;
        else           *(ulla*)(wproj + (g - 12288) * 4) = pk;
    }

    // ---- stage gather tables (coalesced) ----
    for (int i = tid; i < NT * NT; i += 256) s_ridx[i] = ridx[i];
    for (int i = tid; i < 169 * 4; i += 256) s_btab[i] = btab[i];
    {
        const float* mw = mask + (size_t)wdw * NT * NT;
        for (int i = tid; i < NT * NT; i += 256) s_mask[i] = mw[i];
    }
    __syncthreads();

    // ---- emit combined table for this window: 4 heads x 4096 bf16 ----
    // group g encodes (it,jt,qq,cc); the 4 consecutive shorts are r=0..3.
    #pragma unroll
    for (int gi = 0; gi < 4; ++gi) {
        int g = gi * 256 + tid;                       // 0..1023
        int cc = g & 15, qq = (g >> 4) & 3, tile = g >> 6;
        int it = tile >> 2, jt = tile & 3;
        int col = jt * 16 + cc;
        int rowb = it * 16 + qq * 4;
        if (col >= NT) {
            ull m16 = (unsigned short)f2b(-1e30f);
            ull pk = m16 | (m16 << 16) | (m16 << 32) | (m16 << 48);
            #pragma unroll
            for (int h = 0; h < NH; ++h)
                *(ulla*)(cmb + (((size_t)wdw * NH + h) << 12) + g * 4) = pk;
        } else {
            float bt[4][4], mv[4];
            #pragma unroll
            for (int r = 0; r < 4; ++r) {
                int row = rowb + r;
                if (row >= NT) {
                    bt[r][0] = bt[r][1] = bt[r][2] = bt[r][3] = 0.f;
                    mv[r] = 0.f;
                } else {
                    int ri = s_ridx[row * NT + col];
                    float4 b4 = *(const float4*)(s_btab + ri * 4);  // all 4 heads
                    bt[r][0] = b4.x; bt[r][1] = b4.y; bt[r][2] = b4.z; bt[r][3] = b4.w;
                    mv[r] = s_mask[row * NT + col];
                }
            }
            #pragma unroll
            for (int h = 0; h < NH; ++h) {
                ull pk =  (ull)(unsigned short)f2b(bt[0][h] + mv[0])
                        | ((ull)(unsigned short)f2b(bt[1][h] + mv[1]) << 16)
                        | ((ull)(unsigned short)f2b(bt[2][h] + mv[2]) << 32)
                        | ((ull)(unsigned short)f2b(bt[3][h] + mv[3]) << 48);
                *(ulla*)(cmb + (((size_t)wdw * NH + h) << 12) + g * 4) = pk;
            }
        }
    }
}

// LDS pool (32768 B). Per-wave region R=8192 B:
//   Q @+0    [64 rows][32] bf16, XOR-swizzled 8-short groups   = 4096
//   K @+4096 same                                              = 4096
//   P @+0    [64 rows][64] bf16 3-bit-swizzled (overlays Q+K)  = 8192
//   V lives in REGISTERS (16 VGPR) and feeds K=16 PV MFMAs directly.
// Block-shared, phase-disjoint overlays:
//   X @0 [64][136] bf16 = 17408 (dead after barrier 2)
//   O @0 [64][136] bf16 = 17408 (after barrier 3)
// R4 occupancy fix: launch_bounds(256,4) -> 128-reg budget (R3's (256,5)
// forced a 96-reg budget against ~130 live -> 700 MB of scratch spill, 2.5x
// regression). Phase-1 bfn pipeline dropped (-16 VGPR): at 16 waves/CU the
// in-loop B-frag load latency is TLP-hidden, and wqkv is L2-resident.
#define RWAVE 8192
#define OSTR  136
#define LDSB  32768

__global__ __launch_bounds__(256, 4) void wmsa_main(
    const float* __restrict__ x,
    const float* __restrict__ qkvb, const float* __restrict__ projb,
    const short* __restrict__ wqkv, const short* __restrict__ wproj,
    const short* __restrict__ cmb, float* __restrict__ out)
{
    __shared__ __align__(16) char pool[LDSB];
    short* lds = (short*)pool;

    const int b    = blockIdx.x;
    const int wdw  = b & 63;
    const int tid  = threadIdx.x;
    const int wave = tid >> 6;
    const int lane = tid & 63;
    const int qq   = lane >> 4;        // quad 0..3
    const int cc   = lane & 15;
    const int ccl  = cc & 7, cch = cc >> 3, cm3 = cc & 3;

    // ---- prefetch all 6 qkv biases (complete during staging) ----
    const int colbase = wave * 32 + cc;
    float biasv[6];
    #pragma unroll
    for (int j = 0; j < 6; ++j)
        biasv[j] = qkvb[(j >> 1) * DIM + colbase + (j & 1) * 16];

    // ---------------- Phase 0: stage x -> bf16 LDS (stride 136), zero pad rows ----------------
    {
        const float* xb = x + (size_t)b * NT * DIM;
        for (int i = tid; i < NT * 32; i += 256) {
            int t = i >> 5, c4 = (i & 31) << 2;
            float4 v = *(const float4*)(xb + t * DIM + c4);
            ull pk =  (ull)(unsigned short)f2b(v.x)
                    | ((ull)(unsigned short)f2b(v.y) << 16)
                    | ((ull)(unsigned short)f2b(v.z) << 32)
                    | ((ull)(unsigned short)f2b(v.w) << 48);
            *(ulla*)(lds + t * 136 + c4) = pk;
        }
        for (int i = tid; i < (64 - NT) * 32; i += 256) {   // zero rows 49..63
            int t = NT + (i >> 5), c4 = (i & 31) << 2;
            *(ulla*)(lds + t * 136 + c4) = 0ull;
        }
    }
    __syncthreads();   // B1: X staged

    // A-frags of X for all 4 row tiles (held in regs through phase 1)
    short8 af[4][4];
    #pragma unroll
    for (int it = 0; it < 4; ++it)
        #pragma unroll
        for (int ks = 0; ks < 4; ++ks)
            af[it][ks] = *(const short8a*)(lds + (it * 16 + cc) * 136 + ks * 32 + qq * 8);
    __syncthreads();   // B2: X reads done; per-wave regions may be written

    short* qw = (short*)(pool + wave * RWAVE);
    short* kw = qw + 2048;     // +4096 B
    short* pw = qw;            // P overlays Q+K after S

    // V in registers: vq[hlf][it] = 4 consecutive tokens (t0..t0+3, bf16) for
    // dim hlf*16+cc — exactly the 16x16x16 B-frag layout. Static indices only.
    short4v vq[2][4];

    // ---------------- Phase 1: wave h computes Q/K/V of head h ----------------
    #pragma unroll
    for (int jt6 = 0; jt6 < 6; ++jt6) {
        const int sec = jt6 >> 1, hlf = jt6 & 1;             // compile-time
        short8 bfc[4];
        {
            const int cn = sec * DIM + colbase + hlf * 16;
            #pragma unroll
            for (int ks = 0; ks < 4; ++ks)
                bfc[ks] = *(const short8a*)(wqkv + cn * DIM + ks * 32 + qq * 8);
        }
        float bias = biasv[jt6];
        if (sec == 0) bias *= SCALEQ;
        const floatx4 cinit = {bias, bias, bias, bias};
        #pragma unroll
        for (int it = 0; it < 4; ++it) {
            floatx4 acc = cinit;
            #pragma unroll
            for (int ks = 0; ks < 4; ++ks)
                acc = __builtin_amdgcn_mfma_f32_16x16x32_bf16(af[it][ks], bfc[ks], acc, 0, 0, 0);
            if (sec == 2) {                                   // V: stays in registers
                short4v pv;
                pv[0] = f2b(acc[0]); pv[1] = f2b(acc[1]);
                pv[2] = f2b(acc[2]); pv[3] = f2b(acc[3]);
                vq[hlf][it] = pv;
            } else {                                          // Q/K: [t][d] swizzled
                short* dst = (sec == 0) ? qw : kw;
                int gb = hlf * 2 + cch;                       // d>>3
                #pragma unroll
                for (int r = 0; r < 4; ++r) {                 // t&3 == r
                    int t = it * 16 + qq * 4 + r;
                    dst[t * 32 + ((gb ^ r) << 3) + ccl] = f2b(acc[r]);
                }
            }
        }
    }

    // prefetch all 16 S-tile C-inits (bias+mask combined, bf16 frag layout);
    // placed after phase 1 to keep phase-1 VGPR pressure under the budget.
    short4v cm[16];
    {
        const short* cw = cmb + (((size_t)wdw * NH + wave) << 12);
        #pragma unroll
        for (int t16 = 0; t16 < 16; ++t16)
            cm[t16] = *(const short4a*)(cw + t16 * 256 + qq * 64 + cc * 4);
    }
    __asm__ volatile("" ::: "memory");   // intra-wave phase fence: QKV stores -> S loads

    // ---------------- Phase 2: S = Q K^T (+combined C-init), exp, store RAW P ----------------
    // P stored UNNORMALIZED; denominators come from rowsum = P@1 MFMAs in
    // phase 3; O scaled by 1/rowsum after PV. P swizzle is 3-bit:
    // g = (col>>3) ^ (t&3) ^ (((t>>2)&1)<<2) — third bit makes the phase-3
    // b64 reads 2-way banked (free) instead of 4-way.
    {
        short8 qf[4], kf[4];
        #pragma unroll
        for (int t = 0; t < 4; ++t) {
            qf[t] = *(const short8a*)(qw + (t * 16 + cc) * 32 + ((qq ^ cm3) << 3));
            kf[t] = *(const short8a*)(kw + (t * 16 + cc) * 32 + ((qq ^ cm3) << 3));
        }
        #pragma unroll
        for (int it = 0; it < 4; ++it) {
            floatx4 s[4];
            #pragma unroll
            for (int jt = 0; jt < 4; ++jt) {
                short4v cb = cm[it * 4 + jt];
                floatx4 ci = {b2f(cb.x), b2f(cb.y), b2f(cb.z), b2f(cb.w)};
                s[jt] = __builtin_amdgcn_mfma_f32_16x16x32_bf16(qf[it], kf[jt], ci, 0, 0, 0);
            }
            #pragma unroll
            for (int r = 0; r < 4; ++r) {
                int t = it * 16 + qq * 4 + r;
                #pragma unroll
                for (int jt = 0; jt < 4; ++jt) {
                    float ee = __expf(s[jt][r]);   // pads -> exp(-1e30)=0
                    int g = (jt * 2 + cch) ^ r ^ ((qq & 1) << 2);
                    pw[t * 64 + (g << 3) + ccl] = f2b(ee);
                }
            }
        }
    }
    __asm__ volatile("" ::: "memory");   // intra-wave phase fence: P stores -> PV loads

    // ---------------- Phase 3: O = P @ V and rowsum = P @ 1 (K=16 MFMAs, V in regs) ----------------
    floatx4 o[4][2], ssum[4];
    #pragma unroll
    for (int it = 0; it < 4; ++it) {
        o[it][0] = (floatx4){0.f, 0.f, 0.f, 0.f};
        o[it][1] = (floatx4){0.f, 0.f, 0.f, 0.f};
        ssum[it] = (floatx4){0.f, 0.f, 0.f, 0.f};
    }
    const short BONE = (short)0x3F80;    // bf16 1.0
    const short4v ones4 = {BONE, BONE, BONE, BONE};
    #pragma unroll
    for (int rt = 0; rt < 4; ++rt) {
        #pragma unroll
        for (int kt = 0; kt < 4; ++kt) {
            // A-frag: P[row=rt*16+cc][k=kt*16+qq*4..+3], 3-bit swizzle
            int g = (kt * 2 + (qq >> 1)) ^ cm3 ^ (((cc >> 2) & 1) << 2);
            short4v pf = *(const short4a*)(pw + (rt * 16 + cc) * 64 + (g << 3) + (qq & 1) * 4);
            o[rt][0] = MFMA16(pf, vq[0][kt], o[rt][0]);
            o[rt][1] = MFMA16(pf, vq[1][kt], o[rt][1]);
            ssum[rt] = MFMA16(pf, ones4, ssum[rt]);
        }
    }
    // normalize O rows by 1/rowsum (rowsum lands in the same C-layout rows as o)
    #pragma unroll
    for (int it = 0; it < 4; ++it)
        #pragma unroll
        for (int r = 0; r < 4; ++r) {
            float inv = 1.0f / ssum[it][r];
            o[it][0][r] *= inv;
            o[it][1][r] *= inv;
        }

    // prefetch proj B-frags jt=0,1 + all 8 proj biases (issued before the barriers,
    // cannot be sunk past them -> latency overlaps O round-trip)
    short8 pcur[4], pnxt[4];
    float pbv[8];
    #pragma unroll
    for (int ks = 0; ks < 4; ++ks) {
        pcur[ks] = *(const short8a*)(wproj + cc * DIM + ks * 32 + qq * 8);
        pnxt[ks] = *(const short8a*)(wproj + (16 + cc) * DIM + ks * 32 + qq * 8);
    }
    #pragma unroll
    for (int j = 0; j < 8; ++j) pbv[j] = projb[j * 16 + cc];

    __syncthreads();   // B3: all P reads done -> O may overlay per-wave regions

    short* ow = (short*)pool;   // O [64 tokens][OSTR=136], features 0..127
    #pragma unroll
    for (int it = 0; it < 4; ++it)
        #pragma unroll
        for (int jv = 0; jv < 2; ++jv)
            #pragma unroll
            for (int r = 0; r < 4; ++r) {
                int t = it * 16 + qq * 4 + r;
                ow[t * OSTR + wave * 32 + jv * 16 + cc] = f2b(o[it][jv][r]);
            }
    __syncthreads();   // B4: O visible

    // ---------------- Phase 4: proj GEMM (depth-2 pipelined B-frags) ----------------
    {
        short8 a2[4];
        #pragma unroll
        for (int ks = 0; ks < 4; ++ks)
            a2[ks] = *(const short8a*)(ow + (wave * 16 + cc) * OSTR + ks * 32 + qq * 8);
        float* outb = out + (size_t)b * NT * DIM;
        #pragma unroll
        for (int jt = 0; jt < 8; ++jt) {
            short8 pfut[4];
            if (jt < 6) {
                int cn = (jt + 2) * 16 + cc;
                #pragma unroll
                for (int ks = 0; ks < 4; ++ks)
                    pfut[ks] = *(const short8a*)(wproj + cn * DIM + ks * 32 + qq * 8);
            }
            float pb = pbv[jt];
            floatx4 acc = {pb, pb, pb, pb};
            #pragma unroll
            for (int ks = 0; ks < 4; ++ks)
                acc = __builtin_amdgcn_mfma_f32_16x16x32_bf16(a2[ks], pcur[ks], acc, 0, 0, 0);
            int col = jt * 16 + cc;
            #pragma unroll
            for (int r = 0; r < 4; ++r) {
                int row = wave * 16 + qq * 4 + r;
                if (row < NT) outb[row * DIM + col] = acc[r];
            }
            #pragma unroll
            for (int ks = 0; ks < 4; ++ks) { pcur[ks] = pnxt[ks]; pnxt[ks] = pfut[ks]; }
        }
    }
}

extern "C" void kernel_launch(void* const* d_in, const int* in_sizes, int n_in,
                              void* d_out, int out_size, void* d_ws, size_t ws_size,
                              hipStream_t stream) {
    const float* x     = (const float*)d_in[0];   // (4096,49,128)
    const float* mask  = (const float*)d_in[1];   // (64,49,49)
    const float* qkvw  = (const float*)d_in[2];   // (384,128)
    const float* qkvb  = (const float*)d_in[3];   // (384)
    const float* projw = (const float*)d_in[4];   // (128,128)
    const float* projb = (const float*)d_in[5];   // (128)
    const float* btab  = (const float*)d_in[6];   // (169,4)
    const int*   ridx  = (const int*)d_in[7];     // (49,49)
    float* outp = (float*)d_out;

    short* wqkv  = (short*)d_ws;                      //   98304 B
    short* wproj = (short*)((char*)d_ws + 98304);     //   32768 B
    short* cmb   = (short*)((char*)d_ws + 131072);    // 2097152 B (total 2.23 MB)

    wmsa_prep<<<64, 256, 0, stream>>>(qkvw, projw, btab, ridx, mask, wqkv, wproj, cmb);
    wmsa_main<<<4096, 256, 0, stream>>>(x, qkvb, projb, wqkv, wproj, cmb, outp);
}